// Round 1
// baseline (161.122 us; speedup 1.0000x reference)
//
#include <hip/hip_runtime.h>
#include <hip/hip_bf16.h>

#define T_DIM 32772
#define NGROUP 2048

typedef short short8v __attribute__((ext_vector_type(8)));
typedef float float4v __attribute__((ext_vector_type(4)));

// RTNE f32 -> bf16
__device__ __forceinline__ unsigned short f2bf(float f) {
    union { float f; unsigned int u; } c; c.f = f;
    unsigned int u = c.u;
    unsigned int r = (u + 0x7fffu + ((u >> 16) & 1u)) >> 16;
    return (unsigned short)r;
}

// One block per chamfer group g (B*H = 2048).
// x = targ obs rows (n index, 256x128), y = preds obs rows (m index, 256x128).
// loss1 = sum_m min_n P ; loss2 = sum_n min_m P ; P = x2[n] + y2[m] - 2*x.y
__global__ __launch_bounds__(512) void chamfer_kernel(
    const float* __restrict__ preds, const float* __restrict__ targ,
    float* __restrict__ ch_out)
{
    __shared__ __align__(16) unsigned short Ys[128 * 128]; // 32 KB, swizzled bf16 (half of y)
    __shared__ float x2s[256];
    __shared__ float y2s[128];
    __shared__ float colmin_w[8][128];
    __shared__ float red[8];
    __shared__ float loss1_acc;

    const int g = blockIdx.x;
    const float* gx = targ  + (size_t)g * T_DIM + 4;
    const float* gy = preds + (size_t)g * T_DIM + 4;

    const int tid  = threadIdx.x;
    const int lane = tid & 63;
    const int w    = tid >> 6;   // wave 0..7
    const int lg   = lane >> 4;  // lane group 0..3
    const int lc   = lane & 15;

    // ---- x fragments to registers (wave w owns rows [32w, 32w+32)) + x2 ----
    short8v a_frag[2][4];
    #pragma unroll
    for (int ti = 0; ti < 2; ++ti) {
        const float* xr = gx + (size_t)(w * 32 + ti * 16 + lc) * 128;
        float ss = 0.f;
        #pragma unroll
        for (int kk = 0; kk < 4; ++kk) {
            const float4v u0 = *reinterpret_cast<const float4v*>(xr + kk * 32 + lg * 8);
            const float4v u1 = *reinterpret_cast<const float4v*>(xr + kk * 32 + lg * 8 + 4);
            ss += u0[0]*u0[0] + u0[1]*u0[1] + u0[2]*u0[2] + u0[3]*u0[3];
            ss += u1[0]*u1[0] + u1[1]*u1[1] + u1[2]*u1[2] + u1[3]*u1[3];
            short8v af;
            af[0] = (short)f2bf(u0[0]); af[1] = (short)f2bf(u0[1]);
            af[2] = (short)f2bf(u0[2]); af[3] = (short)f2bf(u0[3]);
            af[4] = (short)f2bf(u1[0]); af[5] = (short)f2bf(u1[1]);
            af[6] = (short)f2bf(u1[2]); af[7] = (short)f2bf(u1[3]);
            a_frag[ti][kk] = af;
        }
        // sum over the 4 lane-groups (same row = same lc) -> full x2 row sum
        ss += __shfl_xor(ss, 16);
        ss += __shfl_xor(ss, 32);
        if (lg == 0) x2s[w * 32 + ti * 16 + lc] = ss;
    }
    if (tid == 0) loss1_acc = 0.f;

    float rowmin[2][4];
    #pragma unroll
    for (int ti = 0; ti < 2; ++ti)
        #pragma unroll
        for (int r = 0; r < 4; ++r) rowmin[ti][r] = 1e30f;

    char* Ysb = (char*)Ys;

    for (int hf = 0; hf < 2; ++hf) {
        __syncthreads(); // x2s ready (hf=0); Ys/y2s/red free for reuse (hf=1)

        // ---- stage y half [hf*128, hf*128+128) into LDS (bf16, swizzled) + y2 ----
        const float* gyh = gy + (size_t)hf * 128 * 128;
        #pragma unroll
        for (int i = 0; i < 4; ++i) {
            const int idx = i * 512 + tid;    // 16B-chunk index (8 f32 each)
            const int row = idx >> 4;
            const int cb  = idx & 15;
            const float* src = gyh + row * 128 + cb * 8;
            const float4v u0 = *reinterpret_cast<const float4v*>(src);
            const float4v u1 = *reinterpret_cast<const float4v*>(src + 4);
            float ss = u0[0]*u0[0] + u0[1]*u0[1] + u0[2]*u0[2] + u0[3]*u0[3]
                     + u1[0]*u1[0] + u1[1]*u1[1] + u1[2]*u1[2] + u1[3]*u1[3];
            // 16 lanes share a row
            ss += __shfl_xor(ss, 1);
            ss += __shfl_xor(ss, 2);
            ss += __shfl_xor(ss, 4);
            ss += __shfl_xor(ss, 8);
            if ((lane & 15) == 0) y2s[row] = ss;
            short8v af;
            af[0] = (short)f2bf(u0[0]); af[1] = (short)f2bf(u0[1]);
            af[2] = (short)f2bf(u0[2]); af[3] = (short)f2bf(u0[3]);
            af[4] = (short)f2bf(u1[0]); af[5] = (short)f2bf(u1[1]);
            af[6] = (short)f2bf(u1[2]); af[7] = (short)f2bf(u1[3]);
            const int dst = row * 256 + ((cb * 16) ^ ((row & 7) << 4));
            *reinterpret_cast<short8v*>(Ysb + dst) = af;
        }
        __syncthreads();

        // ---- compute: 8 col-tiles of 16 y-rows each ----
        for (int tj = 0; tj < 8; ++tj) {
            short8v b_frag[4];
            #pragma unroll
            for (int kk = 0; kk < 4; ++kk) {
                const int crow = tj * 16 + lc;
                const int off  = kk * 64 + lg * 16;
                const int addr = crow * 256 + (off ^ ((crow & 7) << 4));
                b_frag[kk] = *reinterpret_cast<const short8v*>(Ysb + addr);
            }
            const float y2c = y2s[tj * 16 + lc];
            float cminv = 1e30f;
            #pragma unroll
            for (int ti = 0; ti < 2; ++ti) {
                float4v acc = {0.f, 0.f, 0.f, 0.f};
                #pragma unroll
                for (int kk = 0; kk < 4; ++kk)
                    acc = __builtin_amdgcn_mfma_f32_16x16x32_bf16(
                        a_frag[ti][kk], b_frag[kk], acc, 0, 0, 0);
                const int rbase = w * 32 + ti * 16 + lg * 4;
                #pragma unroll
                for (int r = 0; r < 4; ++r) {
                    const float P = x2s[rbase + r] + y2c - 2.0f * acc[r];
                    rowmin[ti][r] = fminf(rowmin[ti][r], P);
                    cminv = fminf(cminv, P);
                }
            }
            // col-min over this wave's 32 rows (combine the 4 lane groups)
            cminv = fminf(cminv, __shfl_xor(cminv, 16));
            cminv = fminf(cminv, __shfl_xor(cminv, 32));
            if (lg == 0) colmin_w[w][tj * 16 + lc] = cminv;
        }
        __syncthreads();

        // ---- loss1 partial for this half: min over 8 waves, sum over 128 cols ----
        if (tid < 128) {
            float m = colmin_w[0][tid];
            #pragma unroll
            for (int ww = 1; ww < 8; ++ww) m = fminf(m, colmin_w[ww][tid]);
            #pragma unroll
            for (int s = 1; s < 64; s <<= 1) m += __shfl_xor(m, s);
            if (lane == 0) red[w] = m;
        }
        __syncthreads();
        if (tid == 0) loss1_acc += red[0] + red[1];
    }

    // ---- loss2: row mins (held in registers across both halves) ----
    float s2 = 0.f;
    #pragma unroll
    for (int ti = 0; ti < 2; ++ti)
        #pragma unroll
        for (int r = 0; r < 4; ++r) {
            float v = rowmin[ti][r];
            v = fminf(v, __shfl_xor(v, 1));
            v = fminf(v, __shfl_xor(v, 2));
            v = fminf(v, __shfl_xor(v, 4));
            v = fminf(v, __shfl_xor(v, 8));
            s2 += v; // all 16 lanes of a group now identical
        }
    s2 += __shfl_xor(s2, 16);
    s2 += __shfl_xor(s2, 32);
    __syncthreads(); // protect red[] reuse and loss1_acc write
    if (lane == 0) red[w] = s2;
    __syncthreads();
    if (tid == 0) {
        float l2 = 0.f;
        #pragma unroll
        for (int ww = 0; ww < 8; ++ww) l2 += red[ww];
        ch_out[g] = loss1_acc + l2;
    }
}

// Action loss + final reduction -> out[0], out[1]
__global__ __launch_bounds__(256) void final_kernel(
    const float* __restrict__ preds, const float* __restrict__ targ,
    const float* __restrict__ ch, float* __restrict__ out)
{
    __shared__ float rsw[4], rsa[4], rsc[4];
    const int tid = threadIdx.x;
    const int lane = tid & 63, w = tid >> 6;
    float sw = 0.f, sa0 = 0.f, sc = 0.f;
    for (int p = tid; p < NGROUP; p += 256) {
        const float* pp = preds + (size_t)p * T_DIM;
        const float* tt = targ  + (size_t)p * T_DIM;
        float al = 0.f;
        #pragma unroll
        for (int d = 0; d < 4; ++d) { const float df = pp[d] - tt[d]; al += df * df; }
        al *= 0.25f;
        if ((p & 31) == 0) { sw += 10.f * al; sa0 += al; }
        else               { sw += al; }
        sc += ch[p];
    }
    #pragma unroll
    for (int s = 1; s < 64; s <<= 1) {
        sw  += __shfl_xor(sw, s);
        sa0 += __shfl_xor(sa0, s);
        sc  += __shfl_xor(sc, s);
    }
    if (lane == 0) { rsw[w] = sw; rsa[w] = sa0; rsc[w] = sc; }
    __syncthreads();
    if (tid == 0) {
        float tsw = 0.f, tsa = 0.f, tsc = 0.f;
        #pragma unroll
        for (int i = 0; i < 4; ++i) { tsw += rsw[i]; tsa += rsa[i]; tsc += rsc[i]; }
        out[0] = tsw / 2048.f + tsc / 2048.f;
        out[1] = tsa / 64.f;
    }
}

extern "C" void kernel_launch(void* const* d_in, const int* in_sizes, int n_in,
                              void* d_out, int out_size, void* d_ws, size_t ws_size,
                              hipStream_t stream) {
    const float* preds = (const float*)d_in[0];
    const float* targ  = (const float*)d_in[1];
    float* out = (float*)d_out;
    float* ch  = (float*)d_ws; // 2048 floats of per-group chamfer
    chamfer_kernel<<<NGROUP, 512, 0, stream>>>(preds, targ, ch);
    final_kernel<<<1, 256, 0, stream>>>(preds, targ, ch, out);
}